// Round 10
// baseline (375.711 us; speedup 1.0000x reference)
//
#include <hip/hip_runtime.h>
#include <hip/hip_bf16.h>

// Problem constants (from reference)
#define S 2048
#define W 96
#define E 100
#define H 100
#define PD 50

typedef float f32x4 __attribute__((ext_vector_type(4)));

__device__ __forceinline__ float fast_rcp(float x) { return __builtin_amdgcn_rcpf(x); }

// One DPP reduction stage: x += dpp_move(x). VALU latency, no LDS.
template<int CTRL, int RM, bool BND>
__device__ __forceinline__ float dpp_add(float x) {
    int t = __builtin_amdgcn_update_dpp(0, __float_as_int(x), CTRL, RM, 0xf, BND);
    return x + __int_as_float(t);
}

// Full-wave (64-lane) sum; returns total as a wave-uniform value.
__device__ __forceinline__ float wave_sum_bcast(float x) {
    x = dpp_add<0x111, 0xf, true >(x);  // row_shr:1
    x = dpp_add<0x112, 0xf, true >(x);  // row_shr:2
    x = dpp_add<0x114, 0xf, true >(x);  // row_shr:4
    x = dpp_add<0x118, 0xf, true >(x);  // row_shr:8
    x = dpp_add<0x142, 0xa, false>(x);  // row_bcast:15 -> rows 1,3
    x = dpp_add<0x143, 0xc, false>(x);  // row_bcast:31 -> rows 2,3
    return __int_as_float(__builtin_amdgcn_readlane(__float_as_int(x), 63));
}

// K1: ragged-prefix mean pool over word embeddings + doc_feat accumulation
__global__ __launch_bounds__(128) void k_sent(const int* __restrict__ x,
                                              const float* __restrict__ word_emb,
                                              float* __restrict__ sent,
                                              float* __restrict__ doc_sum) {
    __shared__ int toks[W];
    __shared__ int s_len;
    const int i = blockIdx.x, t = threadIdx.x;
    if (t == 0) s_len = 0;
    __syncthreads();
    if (t < W) {
        int tok = x[i * W + t];
        toks[t] = tok;
        if (tok > 0) atomicAdd(&s_len, 1);
    }
    __syncthreads();
    const int len = s_len;
    if (t < E) {
        float acc = 0.0f;
        for (int j = 0; j < len; ++j)
            acc += word_emb[toks[j] * E + t];   // coalesced across t
        float val = acc / (float)max(len, 1);
        sent[i * E + t] = val;
        atomicAdd(&doc_sum[t], val * (1.0f / (float)S));
    }
}

// K2: doc = tanh(doc_feat @ fc1_w.T + fc1_b); cvec = Wc + Ws @ doc
__global__ __launch_bounds__(128) void k_doc(const float* __restrict__ doc_sum,
                                             const float* __restrict__ fc1_w,
                                             const float* __restrict__ fc1_b,
                                             const float* __restrict__ Wc,
                                             const float* __restrict__ Ws,
                                             float* __restrict__ cvec) {
    __shared__ float s_df[E];
    __shared__ float s_doc[H];
    const int t = threadIdx.x;
    if (t < E) s_df[t] = doc_sum[t];
    __syncthreads();
    if (t < H) {
        float acc = fc1_b[t];
        for (int k = 0; k < E; ++k) acc += s_df[k] * fc1_w[t * E + k];
        s_doc[t] = tanhf(acc);
    }
    __syncthreads();
    if (t < H) {
        float c = Wc[t];
        for (int j = 0; j < H; ++j) c += Ws[t * H + j] * s_doc[j];
        cvec[t] = c;
    }
}

// K3: per-row padded layout for the scan.
// packed row i = 64 float4 slots; slot m = (L2E*hWr[2m], h[2m], L2E*hWr[2m+1], h[2m+1]),
// zeros for k>=100.  Slot 50 .x carries q[i] = -L2E*(h.cvec + pos.Wp + b).
// (dead hWr position: its h is 0, so s stays 0, tanh(s)=0, contribution 0).
// log2e folded into hWr so the scan's sigmoid needs no chain-side scaling.
__global__ __launch_bounds__(128) void k_row(const float* __restrict__ sent,
                                             const float* __restrict__ fc2_w,
                                             const float* __restrict__ fc2_b,
                                             const float* __restrict__ Wr,
                                             const float* __restrict__ cvec,
                                             const float* __restrict__ pos_emb,
                                             const float* __restrict__ Wp,
                                             const float* __restrict__ bptr,
                                             float* __restrict__ packed) {
    __shared__ float s_sent[E];
    __shared__ float s_h[H];
    __shared__ float red[128];
    const int i = blockIdx.x, t = threadIdx.x;
    float* row = packed + (size_t)i * 256;
    if (t < E) s_sent[t] = sent[i * E + t];
    __syncthreads();
    float hv = 0.0f;
    if (t < H) {
        float acc = fc2_b[t];
        for (int k = 0; k < E; ++k) acc += s_sent[k] * fc2_w[t * E + k];
        hv = tanhf(acc);
        s_h[t] = hv;
    }
    __syncthreads();
    {
        const int m = t >> 1, o = (t & 1) * 2;
        if (t < H) {
            float acc = 0.0f;
            for (int k = 0; k < H; ++k) acc += s_h[k] * Wr[k * H + t];   // coalesced across t
            row[m * 4 + o]     = 1.44269504f * acc;  // L2E * hWr
            row[m * 4 + o + 1] = hv;                 // h
        } else {
            if (t != 100) row[m * 4 + o] = 0.0f;   // element 200 reserved for q
            row[m * 4 + o + 1] = 0.0f;
        }
    }
    float p = 0.0f;
    if (t < H) p = hv * cvec[t];
    if (t < PD) p += pos_emb[i * PD + t] * Wp[t];
    red[t] = p;
    __syncthreads();
    for (int m = 64; m > 0; m >>= 1) {
        if (t < m) red[t] += red[t + m];
        __syncthreads();
    }
    if (t == 0) row[200] = -1.44269504f * (red[0] + bptr[0]);  // slot 50 .x
}

// K4: sequential scan, batch-16 double-buffered manual pipeline, pinned
// schedule. Issue->wait distance = 16 serial steps (~4-5k cy) >> HBM latency,
// so memory is provably covered. Chain-trimmed step: exp2 with pre-scaled
// constants, sign-fold via XOR (parallel with exp), no copysign, no chain fma
// for log2e (folded into packed data by k_row).
__global__ __launch_bounds__(64, 1) void k_scan(const f32x4* __restrict__ packed,
                                                float* __restrict__ out) {
    const int l = threadIdx.x;
    const f32x4* pf = packed + l;

    float s0 = 0.0f, s1 = 0.0f, probbuf = 0.0f;

    f32x4 x0, x1, x2, x3, x4, x5, x6, x7, x8, x9, x10, x11, x12, x13, x14, x15;
    f32x4 y0, y1, y2, y3, y4, y5, y6, y7, y8, y9, y10, y11, y12, y13, y14, y15;

#define SB() __builtin_amdgcn_sched_barrier(0)
#define ISSUE(AR, PTR) \
    asm volatile("global_load_dwordx4 %0, %1, off" : "=v"(AR) : "v"(PTR))
#define ISSUE16(P0,P1,P2,P3,P4,P5,P6,P7,P8,P9,P10,P11,P12,P13,P14,P15)       \
    SB();                                                                     \
    ISSUE(P0,  pf +  0 * 64); ISSUE(P1,  pf +  1 * 64);                       \
    ISSUE(P2,  pf +  2 * 64); ISSUE(P3,  pf +  3 * 64);                       \
    ISSUE(P4,  pf +  4 * 64); ISSUE(P5,  pf +  5 * 64);                       \
    ISSUE(P6,  pf +  6 * 64); ISSUE(P7,  pf +  7 * 64);                       \
    ISSUE(P8,  pf +  8 * 64); ISSUE(P9,  pf +  9 * 64);                       \
    ISSUE(P10, pf + 10 * 64); ISSUE(P11, pf + 11 * 64);                       \
    ISSUE(P12, pf + 12 * 64); ISSUE(P13, pf + 13 * 64);                       \
    ISSUE(P14, pf + 14 * 64); ISSUE(P15, pf + 15 * 64);                       \
    pf += 16 * 64;                                                            \
    SB();
#define WAIT_ALL()                                                            \
    SB();                                                                     \
    asm volatile("s_waitcnt vmcnt(0)" ::: "memory");                          \
    SB();

#define STEP(CA_, IDX, G)                                                     \
    {                                                                         \
        const float q = __int_as_float(                                       \
            __builtin_amdgcn_readlane(__float_as_int(CA_.x), 50));            \
        /* e = exp2(-2*log2e*|s|); parallel for s0,s1 */                      \
        float e0 = exp2f(-2.88539008f * fabsf(s0));                           \
        float e1 = exp2f(-2.88539008f * fabsf(s1));                           \
        float g0 = (1.0f - e0) * fast_rcp(1.0f + e0);   /* |tanh| */          \
        float g1 = (1.0f - e1) * fast_rcp(1.0f + e1);                         \
        /* w*sign(s): XOR sign bit, runs parallel with the exp chain */       \
        float w0 = __int_as_float(__float_as_int(CA_.x) ^                     \
                                  (__float_as_int(s0) & 0x80000000));         \
        float w1 = __int_as_float(__float_as_int(CA_.z) ^                     \
                                  (__float_as_int(s1) & 0x80000000));         \
        float part = fmaf(g0, w0, g1 * w1);                                   \
        float total = wave_sum_bcast(part);   /* = log2e * (hWr.tanh(s)) */   \
        float e2 = exp2f(total + q);          /* = exp(total' - pre) */       \
        float prob = fast_rcp(1.0f + e2);                                     \
        s0 = fmaf(CA_.y, prob, s0);                                           \
        s1 = fmaf(CA_.w, prob, s1);                                           \
        probbuf = (l == ((G + IDX) & 63)) ? prob : probbuf;                   \
    }
#define COMPUTE16(P0,P1,P2,P3,P4,P5,P6,P7,P8,P9,P10,P11,P12,P13,P14,P15,G)   \
    STEP(P0,  0, G) STEP(P1,  1, G) STEP(P2,  2, G) STEP(P3,  3, G)           \
    STEP(P4,  4, G) STEP(P5,  5, G) STEP(P6,  6, G) STEP(P7,  7, G)           \
    STEP(P8,  8, G) STEP(P9,  9, G) STEP(P10,10, G) STEP(P11,11, G)           \
    STEP(P12,12, G) STEP(P13,13, G) STEP(P14,14, G) STEP(P15,15, G)           \
    if (((G) & 63) == 48) out[((G) & ~63) + l] = probbuf;

    // Preload batch 0 into X and land it.
    ISSUE16(x0,x1,x2,x3,x4,x5,x6,x7,x8,x9,x10,x11,x12,x13,x14,x15)
    WAIT_ALL()

    for (int base = 0; base < S; base += 32) {
        ISSUE16(y0,y1,y2,y3,y4,y5,y6,y7,y8,y9,y10,y11,y12,y13,y14,y15)  // rows base+16..+31
        COMPUTE16(x0,x1,x2,x3,x4,x5,x6,x7,x8,x9,x10,x11,x12,x13,x14,x15, base)
        WAIT_ALL()                                                      // Y landed long ago
        ISSUE16(x0,x1,x2,x3,x4,x5,x6,x7,x8,x9,x10,x11,x12,x13,x14,x15)  // rows base+32..+47
        COMPUTE16(y0,y1,y2,y3,y4,y5,y6,y7,y8,y9,y10,y11,y12,y13,y14,y15, base + 16)
        WAIT_ALL()                                                      // X landed
    }
#undef COMPUTE16
#undef STEP
#undef WAIT_ALL
#undef ISSUE16
#undef ISSUE
#undef SB
}

extern "C" void kernel_launch(void* const* d_in, const int* in_sizes, int n_in,
                              void* d_out, int out_size, void* d_ws, size_t ws_size,
                              hipStream_t stream) {
    const int*   x        = (const int*)  d_in[0];
    const float* word_emb = (const float*)d_in[1];
    const float* pos_emb  = (const float*)d_in[2];
    const float* fc1_w    = (const float*)d_in[3];
    const float* fc1_b    = (const float*)d_in[4];
    const float* fc2_w    = (const float*)d_in[5];
    const float* fc2_b    = (const float*)d_in[6];
    const float* Wc       = (const float*)d_in[7];
    const float* Ws       = (const float*)d_in[8];
    const float* Wr       = (const float*)d_in[9];
    const float* Wp       = (const float*)d_in[10];
    const float* bptr     = (const float*)d_in[11];
    float* out = (float*)d_out;

    float* wsf      = (float*)d_ws;
    float* doc_sum  = wsf;                 // 128 (zeroed each call)
    float* cvec     = wsf + 128;           // 128
    float* sent     = wsf + 256;           // S*E = 204800
    float* packed   = sent + S * E;        // (S+16)*256 floats, 16B-aligned offset

    hipMemsetAsync(doc_sum, 0, E * sizeof(float), stream);
    hipMemsetAsync(packed + (size_t)S * 256, 0, 16 * 256 * sizeof(float), stream);
    k_sent<<<S, 128, 0, stream>>>(x, word_emb, sent, doc_sum);
    k_doc<<<1, 128, 0, stream>>>(doc_sum, fc1_w, fc1_b, Wc, Ws, cvec);
    k_row<<<S, 128, 0, stream>>>(sent, fc2_w, fc2_b, Wr, cvec, pos_emb, Wp, bptr, packed);
    k_scan<<<1, 64, 0, stream>>>((const f32x4*)packed, out);
}

// Round 11
// 367.789 us; speedup vs baseline: 1.0215x; 1.0215x over previous
//
#include <hip/hip_runtime.h>
#include <hip/hip_bf16.h>

// Problem constants (from reference)
#define S 2048
#define W 96
#define E 100
#define H 100
#define PD 50

typedef float f32x4 __attribute__((ext_vector_type(4)));

__device__ __forceinline__ float fast_rcp(float x) { return __builtin_amdgcn_rcpf(x); }

// One DPP reduction stage: x += dpp_move(x). VALU latency, no LDS.
template<int CTRL, int RM, bool BND>
__device__ __forceinline__ float dpp_add(float x) {
    int t = __builtin_amdgcn_update_dpp(0, __float_as_int(x), CTRL, RM, 0xf, BND);
    return x + __int_as_float(t);
}

// Full-wave (64-lane) sum; returns total as a wave-uniform value.
__device__ __forceinline__ float wave_sum_bcast(float x) {
    x = dpp_add<0x111, 0xf, true >(x);  // row_shr:1
    x = dpp_add<0x112, 0xf, true >(x);  // row_shr:2
    x = dpp_add<0x114, 0xf, true >(x);  // row_shr:4
    x = dpp_add<0x118, 0xf, true >(x);  // row_shr:8
    x = dpp_add<0x142, 0xa, false>(x);  // row_bcast:15 -> rows 1,3
    x = dpp_add<0x143, 0xc, false>(x);  // row_bcast:31 -> rows 2,3
    return __int_as_float(__builtin_amdgcn_readlane(__float_as_int(x), 63));
}

// K1: ragged-prefix mean pool over word embeddings + doc_feat accumulation
__global__ __launch_bounds__(128) void k_sent(const int* __restrict__ x,
                                              const float* __restrict__ word_emb,
                                              float* __restrict__ sent,
                                              float* __restrict__ doc_sum) {
    __shared__ int toks[W];
    __shared__ int s_len;
    const int i = blockIdx.x, t = threadIdx.x;
    if (t == 0) s_len = 0;
    __syncthreads();
    if (t < W) {
        int tok = x[i * W + t];
        toks[t] = tok;
        if (tok > 0) atomicAdd(&s_len, 1);
    }
    __syncthreads();
    const int len = s_len;
    if (t < E) {
        float acc = 0.0f;
        for (int j = 0; j < len; ++j)
            acc += word_emb[toks[j] * E + t];   // coalesced across t
        float val = acc / (float)max(len, 1);
        sent[i * E + t] = val;
        atomicAdd(&doc_sum[t], val * (1.0f / (float)S));
    }
}

// K2: doc = tanh(doc_feat @ fc1_w.T + fc1_b); cvec = Wc + Ws @ doc
__global__ __launch_bounds__(128) void k_doc(const float* __restrict__ doc_sum,
                                             const float* __restrict__ fc1_w,
                                             const float* __restrict__ fc1_b,
                                             const float* __restrict__ Wc,
                                             const float* __restrict__ Ws,
                                             float* __restrict__ cvec) {
    __shared__ float s_df[E];
    __shared__ float s_doc[H];
    const int t = threadIdx.x;
    if (t < E) s_df[t] = doc_sum[t];
    __syncthreads();
    if (t < H) {
        float acc = fc1_b[t];
        for (int k = 0; k < E; ++k) acc += s_df[k] * fc1_w[t * E + k];
        s_doc[t] = tanhf(acc);
    }
    __syncthreads();
    if (t < H) {
        float c = Wc[t];
        for (int j = 0; j < H; ++j) c += Ws[t * H + j] * s_doc[j];
        cvec[t] = c;
    }
}

// K3: per-row padded layout for the scan.
// packed row i = 64 float4 slots; slot m = (L2E*hWr[2m], h[2m], L2E*hWr[2m+1], h[2m+1]),
// zeros for k>=100.  Slot 50 .y (element 201, a dead h-position) carries
// q[i] = -L2E*(h.cvec + pos.Wp + b): the scan injects it into the wave
// reduction via a lane-50 mask, so no readlane is needed for q.
// Dead slots: hWr=0 => no contribution to the dot regardless of their s.
__global__ __launch_bounds__(128) void k_row(const float* __restrict__ sent,
                                             const float* __restrict__ fc2_w,
                                             const float* __restrict__ fc2_b,
                                             const float* __restrict__ Wr,
                                             const float* __restrict__ cvec,
                                             const float* __restrict__ pos_emb,
                                             const float* __restrict__ Wp,
                                             const float* __restrict__ bptr,
                                             float* __restrict__ packed) {
    __shared__ float s_sent[E];
    __shared__ float s_h[H];
    __shared__ float red[128];
    const int i = blockIdx.x, t = threadIdx.x;
    float* row = packed + (size_t)i * 256;
    if (t < E) s_sent[t] = sent[i * E + t];
    __syncthreads();
    float hv = 0.0f;
    if (t < H) {
        float acc = fc2_b[t];
        for (int k = 0; k < E; ++k) acc += s_sent[k] * fc2_w[t * E + k];
        hv = tanhf(acc);
        s_h[t] = hv;
    }
    __syncthreads();
    {
        const int m = t >> 1, o = (t & 1) * 2;
        if (t < H) {
            float acc = 0.0f;
            for (int k = 0; k < H; ++k) acc += s_h[k] * Wr[k * H + t];   // coalesced across t
            row[m * 4 + o]     = 1.44269504f * acc;  // L2E * hWr
            row[m * 4 + o + 1] = hv;                 // h
        } else {
            row[m * 4 + o] = 0.0f;                    // dead hWr (incl. element 200)
            if (t != 100) row[m * 4 + o + 1] = 0.0f;  // element 201 reserved for q
        }
    }
    float p = 0.0f;
    if (t < H) p = hv * cvec[t];
    if (t < PD) p += pos_emb[i * PD + t] * Wp[t];
    red[t] = p;
    __syncthreads();
    for (int m = 64; m > 0; m >>= 1) {
        if (t < m) red[t] += red[t + m];
        __syncthreads();
    }
    if (t == 0) row[201] = -1.44269504f * (red[0] + bptr[0]);  // slot 50 .y
}

// K4: sequential scan, batch-8 double-buffered manual pipeline (R9 structure,
// best measured), pinned schedule. Chain cuts vs R9:
//  - Padé(7,7) |tanh| (continued fraction) + min-clamp: rcp only, no exp.
//    Overshoots 1 for x>4.6 so the clamp is safe; max err ~9e-5.
//  - q injected through the DPP reduction via lane-50 mask (no readlane).
//  - sign applied to w by XOR, parallel to the tanh chain.
__global__ __launch_bounds__(64, 1) void k_scan(const f32x4* __restrict__ packed,
                                                float* __restrict__ out) {
    const int l = threadIdx.x;
    const f32x4* pf = packed + l;
    const float mask50 = (l == 50) ? 1.0f : 0.0f;

    float s0 = 0.0f, s1 = 0.0f, probbuf = 0.0f;

    f32x4 x0, x1, x2, x3, x4, x5, x6, x7;
    f32x4 y0, y1, y2, y3, y4, y5, y6, y7;

#define SB() __builtin_amdgcn_sched_barrier(0)
#define ISSUE(AR, PTR) \
    asm volatile("global_load_dwordx4 %0, %1, off" : "=v"(AR) : "v"(PTR))
#define ISSUE8(P0, P1, P2, P3, P4, P5, P6, P7)                                \
    SB();                                                                     \
    ISSUE(P0, pf + 0 * 64); ISSUE(P1, pf + 1 * 64);                           \
    ISSUE(P2, pf + 2 * 64); ISSUE(P3, pf + 3 * 64);                           \
    ISSUE(P4, pf + 4 * 64); ISSUE(P5, pf + 5 * 64);                           \
    ISSUE(P6, pf + 6 * 64); ISSUE(P7, pf + 7 * 64);                           \
    pf += 8 * 64;                                                             \
    SB();
#define WAIT_ALL()                                                            \
    SB();                                                                     \
    asm volatile("s_waitcnt vmcnt(0)" ::: "memory");                          \
    SB();

#define STEP(CA_, IDX, G)                                                     \
    {                                                                         \
        float ax0 = fabsf(s0), ax1 = fabsf(s1);                               \
        float u0 = ax0 * ax0, u1 = ax1 * ax1;                                 \
        float n0 = fmaf(u0, fmaf(u0, u0 + 378.0f, 17325.0f), 135135.0f);      \
        float d0 = fmaf(u0, fmaf(u0, fmaf(u0, 28.0f, 3150.0f), 62370.0f),     \
                        135135.0f);                                           \
        float n1 = fmaf(u1, fmaf(u1, u1 + 378.0f, 17325.0f), 135135.0f);      \
        float d1 = fmaf(u1, fmaf(u1, fmaf(u1, 28.0f, 3150.0f), 62370.0f),     \
                        135135.0f);                                           \
        float g0 = fminf(ax0 * n0 * fast_rcp(d0), 1.0f);  /* |tanh(s0)| */    \
        float g1 = fminf(ax1 * n1 * fast_rcp(d1), 1.0f);  /* |tanh(s1)| */    \
        /* w*sign(s): XOR sign bit, parallel with the Pade chain */           \
        float w0 = __int_as_float(__float_as_int(CA_.x) ^                     \
                                  (__float_as_int(s0) & 0x80000000));         \
        float w1 = __int_as_float(__float_as_int(CA_.z) ^                     \
                                  (__float_as_int(s1) & 0x80000000));         \
        float part = fmaf(g0, w0, fmaf(g1, w1, mask50 * CA_.y));              \
        float total = wave_sum_bcast(part);  /* = L2E*(hWr.tanh(s) - pre) */  \
        float e2 = exp2f(total);                                              \
        float prob = fast_rcp(1.0f + e2);                                     \
        s0 = fmaf(CA_.y, prob, s0);   /* lane50: s0 += q*prob, harmless */    \
        s1 = fmaf(CA_.w, prob, s1);                                           \
        probbuf = (l == ((G + IDX) & 63)) ? prob : probbuf;                   \
    }
#define COMPUTE8(P0, P1, P2, P3, P4, P5, P6, P7, G)                           \
    STEP(P0, 0, G) STEP(P1, 1, G) STEP(P2, 2, G) STEP(P3, 3, G)               \
    STEP(P4, 4, G) STEP(P5, 5, G) STEP(P6, 6, G) STEP(P7, 7, G)               \
    if (((G) & 63) == 56) out[((G) & ~63) + l] = probbuf;

    // Preload batch 0 into X and land it.
    ISSUE8(x0, x1, x2, x3, x4, x5, x6, x7)
    WAIT_ALL()

    for (int base = 0; base < S; base += 16) {
        ISSUE8(y0, y1, y2, y3, y4, y5, y6, y7)            // rows base+8..base+15
        COMPUTE8(x0, x1, x2, x3, x4, x5, x6, x7, base)    // rows base..base+7
        WAIT_ALL()                                        // Y landed (issued ~1500cy ago)
        ISSUE8(x0, x1, x2, x3, x4, x5, x6, x7)            // rows base+16..base+23
        COMPUTE8(y0, y1, y2, y3, y4, y5, y6, y7, base + 8)
        WAIT_ALL()                                        // X landed
    }
#undef COMPUTE8
#undef STEP
#undef WAIT_ALL
#undef ISSUE8
#undef ISSUE
#undef SB
}

extern "C" void kernel_launch(void* const* d_in, const int* in_sizes, int n_in,
                              void* d_out, int out_size, void* d_ws, size_t ws_size,
                              hipStream_t stream) {
    const int*   x        = (const int*)  d_in[0];
    const float* word_emb = (const float*)d_in[1];
    const float* pos_emb  = (const float*)d_in[2];
    const float* fc1_w    = (const float*)d_in[3];
    const float* fc1_b    = (const float*)d_in[4];
    const float* fc2_w    = (const float*)d_in[5];
    const float* fc2_b    = (const float*)d_in[6];
    const float* Wc       = (const float*)d_in[7];
    const float* Ws       = (const float*)d_in[8];
    const float* Wr       = (const float*)d_in[9];
    const float* Wp       = (const float*)d_in[10];
    const float* bptr     = (const float*)d_in[11];
    float* out = (float*)d_out;

    float* wsf      = (float*)d_ws;
    float* doc_sum  = wsf;                 // 128 (zeroed each call)
    float* cvec     = wsf + 128;           // 128
    float* sent     = wsf + 256;           // S*E = 204800
    float* packed   = sent + S * E;        // (S+16)*256 floats, 16B-aligned offset

    hipMemsetAsync(doc_sum, 0, E * sizeof(float), stream);
    hipMemsetAsync(packed + (size_t)S * 256, 0, 16 * 256 * sizeof(float), stream);
    k_sent<<<S, 128, 0, stream>>>(x, word_emb, sent, doc_sum);
    k_doc<<<1, 128, 0, stream>>>(doc_sum, fc1_w, fc1_b, Wc, Ws, cvec);
    k_row<<<S, 128, 0, stream>>>(sent, fc2_w, fc2_b, Wr, cvec, pos_emb, Wp, bptr, packed);
    k_scan<<<1, 64, 0, stream>>>((const f32x4*)packed, out);
}

// Round 12
// 332.652 us; speedup vs baseline: 1.1294x; 1.1056x over previous
//
#include <hip/hip_runtime.h>
#include <hip/hip_bf16.h>

// Problem constants (from reference)
#define S 2048
#define W 96
#define E 100
#define H 100
#define PD 50

typedef float f32x4 __attribute__((ext_vector_type(4)));

__device__ __forceinline__ float fast_rcp(float x) { return __builtin_amdgcn_rcpf(x); }

// One DPP reduction stage: x += dpp_move(x). VALU latency, no LDS.
template<int CTRL, int RM, bool BND>
__device__ __forceinline__ float dpp_add(float x) {
    int t = __builtin_amdgcn_update_dpp(0, __float_as_int(x), CTRL, RM, 0xf, BND);
    return x + __int_as_float(t);
}

// Full-wave (64-lane) sum; returns total as a wave-uniform value.
__device__ __forceinline__ float wave_sum_bcast(float x) {
    x = dpp_add<0x111, 0xf, true >(x);  // row_shr:1
    x = dpp_add<0x112, 0xf, true >(x);  // row_shr:2
    x = dpp_add<0x114, 0xf, true >(x);  // row_shr:4
    x = dpp_add<0x118, 0xf, true >(x);  // row_shr:8
    x = dpp_add<0x142, 0xa, false>(x);  // row_bcast:15 -> rows 1,3
    x = dpp_add<0x143, 0xc, false>(x);  // row_bcast:31 -> rows 2,3
    return __int_as_float(__builtin_amdgcn_readlane(__float_as_int(x), 63));
}

// K1: ragged-prefix mean pool over word embeddings + doc_feat accumulation
__global__ __launch_bounds__(128) void k_sent(const int* __restrict__ x,
                                              const float* __restrict__ word_emb,
                                              float* __restrict__ sent,
                                              float* __restrict__ doc_sum) {
    __shared__ int toks[W];
    __shared__ int s_len;
    const int i = blockIdx.x, t = threadIdx.x;
    if (t == 0) s_len = 0;
    __syncthreads();
    if (t < W) {
        int tok = x[i * W + t];
        toks[t] = tok;
        if (tok > 0) atomicAdd(&s_len, 1);
    }
    __syncthreads();
    const int len = s_len;
    if (t < E) {
        float acc = 0.0f;
        for (int j = 0; j < len; ++j)
            acc += word_emb[toks[j] * E + t];   // coalesced across t
        float val = acc / (float)max(len, 1);
        sent[i * E + t] = val;
        atomicAdd(&doc_sum[t], val * (1.0f / (float)S));
    }
}

// K2: doc = tanh(doc_feat @ fc1_w.T + fc1_b); cvec = Wc + Ws @ doc
__global__ __launch_bounds__(128) void k_doc(const float* __restrict__ doc_sum,
                                             const float* __restrict__ fc1_w,
                                             const float* __restrict__ fc1_b,
                                             const float* __restrict__ Wc,
                                             const float* __restrict__ Ws,
                                             float* __restrict__ cvec) {
    __shared__ float s_df[E];
    __shared__ float s_doc[H];
    const int t = threadIdx.x;
    if (t < E) s_df[t] = doc_sum[t];
    __syncthreads();
    if (t < H) {
        float acc = fc1_b[t];
        for (int k = 0; k < E; ++k) acc += s_df[k] * fc1_w[t * E + k];
        s_doc[t] = tanhf(acc);
    }
    __syncthreads();
    if (t < H) {
        float c = Wc[t];
        for (int j = 0; j < H; ++j) c += Ws[t * H + j] * s_doc[j];
        cvec[t] = c;
    }
}

// K3: per-row padded layout for the scan.
// packed row i = 64 float4 slots; slot m = (L2E*hWr[2m], h[2m], L2E*hWr[2m+1], h[2m+1]),
// zeros for k>=100.  Slot 50 .x (element 200, a DEAD hWr position) carries
// q[i] = -L2E*(h.cvec + pos.Wp + b): the scan injects it additively into the
// wave reduction via a lane-50 mask (part += mq*ca.x). Lane 50's own state
// stays exactly 0 (its h entries are 0 => delta=0), so q never pollutes it.
__global__ __launch_bounds__(128) void k_row(const float* __restrict__ sent,
                                             const float* __restrict__ fc2_w,
                                             const float* __restrict__ fc2_b,
                                             const float* __restrict__ Wr,
                                             const float* __restrict__ cvec,
                                             const float* __restrict__ pos_emb,
                                             const float* __restrict__ Wp,
                                             const float* __restrict__ bptr,
                                             float* __restrict__ packed) {
    __shared__ float s_sent[E];
    __shared__ float s_h[H];
    __shared__ float red[128];
    const int i = blockIdx.x, t = threadIdx.x;
    float* row = packed + (size_t)i * 256;
    if (t < E) s_sent[t] = sent[i * E + t];
    __syncthreads();
    float hv = 0.0f;
    if (t < H) {
        float acc = fc2_b[t];
        for (int k = 0; k < E; ++k) acc += s_sent[k] * fc2_w[t * E + k];
        hv = tanhf(acc);
        s_h[t] = hv;
    }
    __syncthreads();
    {
        const int m = t >> 1, o = (t & 1) * 2;
        if (t < H) {
            float acc = 0.0f;
            for (int k = 0; k < H; ++k) acc += s_h[k] * Wr[k * H + t];   // coalesced across t
            row[m * 4 + o]     = 1.44269504f * acc;  // L2E * hWr
            row[m * 4 + o + 1] = hv;                 // h
        } else {
            if (t != 100) row[m * 4 + o] = 0.0f;   // dead w (element 200 reserved for q)
            row[m * 4 + o + 1] = 0.0f;             // dead h
        }
    }
    float p = 0.0f;
    if (t < H) p = hv * cvec[t];
    if (t < PD) p += pos_emb[i * PD + t] * Wp[t];
    red[t] = p;
    __syncthreads();
    for (int m = 64; m > 0; m >>= 1) {
        if (t < m) red[t] += red[t + m];
        __syncthreads();
    }
    if (t == 0) row[200] = -1.44269504f * (red[0] + bptr[0]);  // slot 50 .x
}

// K4: sequential scan, batch-8 double-buffered manual pipeline (R9 structure),
// pinned schedule. State = t = tanh(s) maintained via the EXACT tanh addition
// formula: tanh(s+d) = (t + T)/(1 + t*T), T = tanh(d) by 5th-order odd series
// (|d| <= |h| << 1 so series error ~1e-8). Removes both tanh transcendentals
// from the chain (one rcp remains); no fabs/copysign/XOR needed.
__global__ __launch_bounds__(64, 1) void k_scan(const f32x4* __restrict__ packed,
                                                float* __restrict__ out) {
    const int l = threadIdx.x;
    const f32x4* pf = packed + l;
    const float mq = (l == 50) ? 1.0f : 0.0f;

    float t0 = 0.0f, t1 = 0.0f, probbuf = 0.0f;   // t = tanh(s), s starts at 0

    f32x4 x0, x1, x2, x3, x4, x5, x6, x7;
    f32x4 y0, y1, y2, y3, y4, y5, y6, y7;

#define SB() __builtin_amdgcn_sched_barrier(0)
#define ISSUE(AR, PTR) \
    asm volatile("global_load_dwordx4 %0, %1, off" : "=v"(AR) : "v"(PTR))
#define ISSUE8(P0, P1, P2, P3, P4, P5, P6, P7)                                \
    SB();                                                                     \
    ISSUE(P0, pf + 0 * 64); ISSUE(P1, pf + 1 * 64);                           \
    ISSUE(P2, pf + 2 * 64); ISSUE(P3, pf + 3 * 64);                           \
    ISSUE(P4, pf + 4 * 64); ISSUE(P5, pf + 5 * 64);                           \
    ISSUE(P6, pf + 6 * 64); ISSUE(P7, pf + 7 * 64);                           \
    pf += 8 * 64;                                                             \
    SB();
#define WAIT_ALL()                                                            \
    SB();                                                                     \
    asm volatile("s_waitcnt vmcnt(0)" ::: "memory");                          \
    SB();

#define STEP(CA_, IDX, G)                                                     \
    {                                                                         \
        /* logit sum: t.(L2E*hWr) + q (lane-50 additive injection) */         \
        float part = fmaf(t0, CA_.x, fmaf(t1, CA_.z, mq * CA_.x));            \
        float total = wave_sum_bcast(part);  /* = L2E*(hWr.tanh(s) - pre) */  \
        float e2 = exp2f(total);                                              \
        float prob = fast_rcp(1.0f + e2);                                     \
        /* state update: tanh addition formula, T = tanh(h*prob) by series */ \
        float d0 = CA_.y * prob, d1 = CA_.w * prob;                           \
        float u0 = d0 * d0, u1 = d1 * d1;                                     \
        float T0 = d0 * fmaf(u0, fmaf(u0, 0.13333334f, -0.33333334f), 1.0f);  \
        float T1 = d1 * fmaf(u1, fmaf(u1, 0.13333334f, -0.33333334f), 1.0f);  \
        float r0 = fast_rcp(fmaf(t0, T0, 1.0f));                              \
        float r1 = fast_rcp(fmaf(t1, T1, 1.0f));                              \
        t0 = (t0 + T0) * r0;                                                  \
        t1 = (t1 + T1) * r1;                                                  \
        probbuf = (l == ((G + IDX) & 63)) ? prob : probbuf;                   \
    }
#define COMPUTE8(P0, P1, P2, P3, P4, P5, P6, P7, G)                           \
    STEP(P0, 0, G) STEP(P1, 1, G) STEP(P2, 2, G) STEP(P3, 3, G)               \
    STEP(P4, 4, G) STEP(P5, 5, G) STEP(P6, 6, G) STEP(P7, 7, G)               \
    if (((G) & 63) == 56) out[((G) & ~63) + l] = probbuf;

    // Preload batch 0 into X and land it.
    ISSUE8(x0, x1, x2, x3, x4, x5, x6, x7)
    WAIT_ALL()

    for (int base = 0; base < S; base += 16) {
        ISSUE8(y0, y1, y2, y3, y4, y5, y6, y7)            // rows base+8..base+15
        COMPUTE8(x0, x1, x2, x3, x4, x5, x6, x7, base)    // rows base..base+7
        WAIT_ALL()                                        // Y landed (issued ~1500cy ago)
        ISSUE8(x0, x1, x2, x3, x4, x5, x6, x7)            // rows base+16..base+23
        COMPUTE8(y0, y1, y2, y3, y4, y5, y6, y7, base + 8)
        WAIT_ALL()                                        // X landed
    }
#undef COMPUTE8
#undef STEP
#undef WAIT_ALL
#undef ISSUE8
#undef ISSUE
#undef SB
}

extern "C" void kernel_launch(void* const* d_in, const int* in_sizes, int n_in,
                              void* d_out, int out_size, void* d_ws, size_t ws_size,
                              hipStream_t stream) {
    const int*   x        = (const int*)  d_in[0];
    const float* word_emb = (const float*)d_in[1];
    const float* pos_emb  = (const float*)d_in[2];
    const float* fc1_w    = (const float*)d_in[3];
    const float* fc1_b    = (const float*)d_in[4];
    const float* fc2_w    = (const float*)d_in[5];
    const float* fc2_b    = (const float*)d_in[6];
    const float* Wc       = (const float*)d_in[7];
    const float* Ws       = (const float*)d_in[8];
    const float* Wr       = (const float*)d_in[9];
    const float* Wp       = (const float*)d_in[10];
    const float* bptr     = (const float*)d_in[11];
    float* out = (float*)d_out;

    float* wsf      = (float*)d_ws;
    float* doc_sum  = wsf;                 // 128 (zeroed each call)
    float* cvec     = wsf + 128;           // 128
    float* sent     = wsf + 256;           // S*E = 204800
    float* packed   = sent + S * E;        // (S+16)*256 floats, 16B-aligned offset

    hipMemsetAsync(doc_sum, 0, E * sizeof(float), stream);
    hipMemsetAsync(packed + (size_t)S * 256, 0, 16 * 256 * sizeof(float), stream);
    k_sent<<<S, 128, 0, stream>>>(x, word_emb, sent, doc_sum);
    k_doc<<<1, 128, 0, stream>>>(doc_sum, fc1_w, fc1_b, Wc, Ws, cvec);
    k_row<<<S, 128, 0, stream>>>(sent, fc2_w, fc2_b, Wr, cvec, pos_emb, Wp, bptr, packed);
    k_scan<<<1, 64, 0, stream>>>((const f32x4*)packed, out);
}

// Round 13
// 316.660 us; speedup vs baseline: 1.1865x; 1.0505x over previous
//
#include <hip/hip_runtime.h>
#include <hip/hip_bf16.h>

// Problem constants (from reference)
#define S 2048
#define W 96
#define E 100
#define H 100
#define PD 50

typedef float f32x4 __attribute__((ext_vector_type(4)));

__device__ __forceinline__ float fast_rcp(float x) { return __builtin_amdgcn_rcpf(x); }

// One DPP reduction stage: x += dpp_move(x). VALU latency, no LDS.
template<int CTRL, int RM, bool BND>
__device__ __forceinline__ float dpp_add(float x) {
    int t = __builtin_amdgcn_update_dpp(0, __float_as_int(x), CTRL, RM, 0xf, BND);
    return x + __int_as_float(t);
}

// Full-wave (64-lane) sum; returns total as a wave-uniform value.
__device__ __forceinline__ float wave_sum_bcast(float x) {
    x = dpp_add<0x111, 0xf, true >(x);  // row_shr:1
    x = dpp_add<0x112, 0xf, true >(x);  // row_shr:2
    x = dpp_add<0x114, 0xf, true >(x);  // row_shr:4
    x = dpp_add<0x118, 0xf, true >(x);  // row_shr:8
    x = dpp_add<0x142, 0xa, false>(x);  // row_bcast:15 -> rows 1,3
    x = dpp_add<0x143, 0xc, false>(x);  // row_bcast:31 -> rows 2,3
    return __int_as_float(__builtin_amdgcn_readlane(__float_as_int(x), 63));
}

// K1: ragged-prefix mean pool over word embeddings + doc_feat accumulation
__global__ __launch_bounds__(128) void k_sent(const int* __restrict__ x,
                                              const float* __restrict__ word_emb,
                                              float* __restrict__ sent,
                                              float* __restrict__ doc_sum) {
    __shared__ int toks[W];
    __shared__ int s_len;
    const int i = blockIdx.x, t = threadIdx.x;
    if (t == 0) s_len = 0;
    __syncthreads();
    if (t < W) {
        int tok = x[i * W + t];
        toks[t] = tok;
        if (tok > 0) atomicAdd(&s_len, 1);
    }
    __syncthreads();
    const int len = s_len;
    if (t < E) {
        float acc = 0.0f;
        for (int j = 0; j < len; ++j)
            acc += word_emb[toks[j] * E + t];   // coalesced across t
        float val = acc / (float)max(len, 1);
        sent[i * E + t] = val;
        atomicAdd(&doc_sum[t], val * (1.0f / (float)S));
    }
}

// K2: doc = tanh(doc_feat @ fc1_w.T + fc1_b); cvec = Wc + Ws @ doc
__global__ __launch_bounds__(128) void k_doc(const float* __restrict__ doc_sum,
                                             const float* __restrict__ fc1_w,
                                             const float* __restrict__ fc1_b,
                                             const float* __restrict__ Wc,
                                             const float* __restrict__ Ws,
                                             float* __restrict__ cvec) {
    __shared__ float s_df[E];
    __shared__ float s_doc[H];
    const int t = threadIdx.x;
    if (t < E) s_df[t] = doc_sum[t];
    __syncthreads();
    if (t < H) {
        float acc = fc1_b[t];
        for (int k = 0; k < E; ++k) acc += s_df[k] * fc1_w[t * E + k];
        s_doc[t] = tanhf(acc);
    }
    __syncthreads();
    if (t < H) {
        float c = Wc[t];
        for (int j = 0; j < H; ++j) c += Ws[t * H + j] * s_doc[j];
        cvec[t] = c;
    }
}

// K3: per-row padded layout for the scan.
// packed row i = 64 float4 slots; slot m = (L2E*hWr[2m], h[2m], L2E*hWr[2m+1], h[2m+1]),
// zeros for k>=100.  Slot 50 .x (element 200, a DEAD hWr position) carries
// q[i] = -L2E*(h.cvec + pos.Wp + b). The scan sets lane 50's t0 = 1, so
// part(lane50) = t0*q contributes q to the wave sum with no extra fma.
__global__ __launch_bounds__(128) void k_row(const float* __restrict__ sent,
                                             const float* __restrict__ fc2_w,
                                             const float* __restrict__ fc2_b,
                                             const float* __restrict__ Wr,
                                             const float* __restrict__ cvec,
                                             const float* __restrict__ pos_emb,
                                             const float* __restrict__ Wp,
                                             const float* __restrict__ bptr,
                                             float* __restrict__ packed) {
    __shared__ float s_sent[E];
    __shared__ float s_h[H];
    __shared__ float red[128];
    const int i = blockIdx.x, t = threadIdx.x;
    float* row = packed + (size_t)i * 256;
    if (t < E) s_sent[t] = sent[i * E + t];
    __syncthreads();
    float hv = 0.0f;
    if (t < H) {
        float acc = fc2_b[t];
        for (int k = 0; k < E; ++k) acc += s_sent[k] * fc2_w[t * E + k];
        hv = tanhf(acc);
        s_h[t] = hv;
    }
    __syncthreads();
    {
        const int m = t >> 1, o = (t & 1) * 2;
        if (t < H) {
            float acc = 0.0f;
            for (int k = 0; k < H; ++k) acc += s_h[k] * Wr[k * H + t];   // coalesced across t
            row[m * 4 + o]     = 1.44269504f * acc;  // L2E * hWr
            row[m * 4 + o + 1] = hv;                 // h
        } else {
            if (t != 100) row[m * 4 + o] = 0.0f;   // dead w (element 200 reserved for q)
            row[m * 4 + o + 1] = 0.0f;             // dead h
        }
    }
    float p = 0.0f;
    if (t < H) p = hv * cvec[t];
    if (t < PD) p += pos_emb[i * PD + t] * Wp[t];
    red[t] = p;
    __syncthreads();
    for (int m = 64; m > 0; m >>= 1) {
        if (t < m) red[t] += red[t + m];
        __syncthreads();
    }
    if (t == 0) row[200] = -1.44269504f * (red[0] + bptr[0]);  // slot 50 .x
}

// K4: sequential scan, batch-8 double-buffered manual pipeline (R9 structure),
// pinned schedule. ONE rcp on the recurrence chain:
//   a = 1 + 2^total  (prob = 1/a, off-chain, output only)
//   T = d - d^3/3, d = h/a  (|d|<=0.2, dropped d^5 term ~4e-5 worst-case)
//   tanh-addition, scaled by a^3:  inner = h*a^2 - h^3/3  (h^3/3 off-chain)
//   N = t*a^3 + inner;  D = a^3 + t*inner;  t' = N * rcp(D)
// Overflow: |total| <= ~10 (weights 0.05-scale) => a^3 <= 2^30, huge margin.
// Lane 50: t0 = 1 forever (its h = 0 => inner = 0 => t' = t*a3*rcp(a3) ~ 1),
// so its w-slot (= q) is injected into the wave sum for free.
__global__ __launch_bounds__(64, 1) void k_scan(const f32x4* __restrict__ packed,
                                                float* __restrict__ out) {
    const int l = threadIdx.x;
    const f32x4* pf = packed + l;

    float t0 = (l == 50) ? 1.0f : 0.0f;   // t = tanh(s); lane50 carries q
    float t1 = 0.0f, probbuf = 0.0f;

    f32x4 x0, x1, x2, x3, x4, x5, x6, x7;
    f32x4 y0, y1, y2, y3, y4, y5, y6, y7;

#define SB() __builtin_amdgcn_sched_barrier(0)
#define ISSUE(AR, PTR) \
    asm volatile("global_load_dwordx4 %0, %1, off" : "=v"(AR) : "v"(PTR))
#define ISSUE8(P0, P1, P2, P3, P4, P5, P6, P7)                                \
    SB();                                                                     \
    ISSUE(P0, pf + 0 * 64); ISSUE(P1, pf + 1 * 64);                           \
    ISSUE(P2, pf + 2 * 64); ISSUE(P3, pf + 3 * 64);                           \
    ISSUE(P4, pf + 4 * 64); ISSUE(P5, pf + 5 * 64);                           \
    ISSUE(P6, pf + 6 * 64); ISSUE(P7, pf + 7 * 64);                           \
    pf += 8 * 64;                                                             \
    SB();
#define WAIT_ALL()                                                            \
    SB();                                                                     \
    asm volatile("s_waitcnt vmcnt(0)" ::: "memory");                          \
    SB();

#define STEP(CA_, IDX, G)                                                     \
    {                                                                         \
        /* off-chain: h^3/3 (from loaded data, lands a full batch early) */   \
        float h30 = CA_.y * CA_.y * CA_.y * 0.33333334f;                      \
        float h31 = CA_.w * CA_.w * CA_.w * 0.33333334f;                      \
        float part = fmaf(t0, CA_.x, t1 * CA_.z);                             \
        float total = wave_sum_bcast(part);  /* = L2E*(hWr.tanh(s) - pre) */  \
        float e2 = exp2f(total);                                              \
        float a  = e2 + 1.0f;                                                 \
        float a2 = a * a;                                                     \
        float a3 = a2 * a;                                                    \
        float in0 = fmaf(CA_.y, a2, -h30);                                    \
        float in1 = fmaf(CA_.w, a2, -h31);                                    \
        float N0 = fmaf(t0, a3, in0), D0 = fmaf(t0, in0, a3);                 \
        float N1 = fmaf(t1, a3, in1), D1 = fmaf(t1, in1, a3);                 \
        t0 = N0 * fast_rcp(D0);                                               \
        t1 = N1 * fast_rcp(D1);                                               \
        float prob = fast_rcp(a);            /* off the recurrence chain */   \
        probbuf = (l == ((G + IDX) & 63)) ? prob : probbuf;                   \
    }
#define COMPUTE8(P0, P1, P2, P3, P4, P5, P6, P7, G)                           \
    STEP(P0, 0, G) STEP(P1, 1, G) STEP(P2, 2, G) STEP(P3, 3, G)               \
    STEP(P4, 4, G) STEP(P5, 5, G) STEP(P6, 6, G) STEP(P7, 7, G)               \
    if (((G) & 63) == 56) out[((G) & ~63) + l] = probbuf;

    // Preload batch 0 into X and land it.
    ISSUE8(x0, x1, x2, x3, x4, x5, x6, x7)
    WAIT_ALL()

    for (int base = 0; base < S; base += 16) {
        ISSUE8(y0, y1, y2, y3, y4, y5, y6, y7)            // rows base+8..base+15
        COMPUTE8(x0, x1, x2, x3, x4, x5, x6, x7, base)    // rows base..base+7
        WAIT_ALL()                                        // Y landed (issued ~1500cy ago)
        ISSUE8(x0, x1, x2, x3, x4, x5, x6, x7)            // rows base+16..base+23
        COMPUTE8(y0, y1, y2, y3, y4, y5, y6, y7, base + 8)
        WAIT_ALL()                                        // X landed
    }
#undef COMPUTE8
#undef STEP
#undef WAIT_ALL
#undef ISSUE8
#undef ISSUE
#undef SB
}

extern "C" void kernel_launch(void* const* d_in, const int* in_sizes, int n_in,
                              void* d_out, int out_size, void* d_ws, size_t ws_size,
                              hipStream_t stream) {
    const int*   x        = (const int*)  d_in[0];
    const float* word_emb = (const float*)d_in[1];
    const float* pos_emb  = (const float*)d_in[2];
    const float* fc1_w    = (const float*)d_in[3];
    const float* fc1_b    = (const float*)d_in[4];
    const float* fc2_w    = (const float*)d_in[5];
    const float* fc2_b    = (const float*)d_in[6];
    const float* Wc       = (const float*)d_in[7];
    const float* Ws       = (const float*)d_in[8];
    const float* Wr       = (const float*)d_in[9];
    const float* Wp       = (const float*)d_in[10];
    const float* bptr     = (const float*)d_in[11];
    float* out = (float*)d_out;

    float* wsf      = (float*)d_ws;
    float* doc_sum  = wsf;                 // 128 (zeroed each call)
    float* cvec     = wsf + 128;           // 128
    float* sent     = wsf + 256;           // S*E = 204800
    float* packed   = sent + S * E;        // (S+16)*256 floats, 16B-aligned offset

    hipMemsetAsync(doc_sum, 0, E * sizeof(float), stream);
    hipMemsetAsync(packed + (size_t)S * 256, 0, 16 * 256 * sizeof(float), stream);
    k_sent<<<S, 128, 0, stream>>>(x, word_emb, sent, doc_sum);
    k_doc<<<1, 128, 0, stream>>>(doc_sum, fc1_w, fc1_b, Wc, Ws, cvec);
    k_row<<<S, 128, 0, stream>>>(sent, fc2_w, fc2_b, Wr, cvec, pos_emb, Wp, bptr, packed);
    k_scan<<<1, 64, 0, stream>>>((const f32x4*)packed, out);
}